// Round 6
// baseline (723.519 us; speedup 1.0000x reference)
//
#include <hip/hip_runtime.h>
#include <hip/hip_bf16.h>
#include <math.h>
#include <stdint.h>

#define N_TOKENS 16384
#define DIM 4096
#define NEXP 64

typedef const __attribute__((address_space(1))) void gvoid_t;
typedef __attribute__((address_space(3))) void svoid_t;

constexpr int MT = 64;   // tokens per block (lane = token)
constexpr int KC = 128;  // k-chunk staged per iteration (32 x 16B slots)
constexpr int TN = 16;   // experts per wave (wave-uniform -> scalar W loads)

// ---------------- K1: logits = x @ W^T (fp32, K-split partials) ----------------
// lane = token. Wave w owns experts [16w,16w+16) -> W addresses are
// WAVE-UNIFORM -> compiler emits s_load (scalar pipe, K$/L2), consumed as the
// SGPR operand of v_fma. W never touches LDS or vector memory.
// x: double-buffered LDS via global_load_lds, source-XOR-swizzled slots
// (slot ^= row&31), linear dest; compute read is ds_read_b128, conflict-free
// (lanes l and l+32 are a free 2-way broadcast).
__global__ __launch_bounds__(256, 2) void k1_gemm(const float* __restrict__ x,
                                                  const float* __restrict__ W,
                                                  float* __restrict__ P, int KS) {
  __shared__ float xlds[2][MT * KC];  // 2 x 32 KB
  const int tid = threadIdx.x;
  const int lane = tid & 63;  // token within block
  const int wid = __builtin_amdgcn_readfirstlane(tid >> 6);  // wave 0..3
  const int tok0 = blockIdx.x * MT;
  const int k0 = blockIdx.y * KS;
  const int ew0 = wid * TN;  // wave-uniform expert base

  const int lr = lane >> 5;   // row within one glds instr (2 rows x 512B)
  const int ls = lane & 31;   // 16B slot within row
  const int key = lane & 31;  // compute-read swizzle key (row = lane)

  float acc[TN] = {};

  // stage x[tok0..+63][kc..+127] into xlds[b]: 8 glds/wave, 2 rows (1KB) each.
  auto stage = [&](int b, int kc) {
#pragma unroll
    for (int q = 0; q < 8; ++q) {
      const int r0 = wid * 16 + q * 2;  // wave-uniform row base
      const int r = r0 + lr;
      const float* src =
          x + (size_t)(tok0 + r) * DIM + kc + 4 * (ls ^ (r & 31));
      float* dst = &xlds[b][r0 * KC];
      __builtin_amdgcn_global_load_lds((gvoid_t*)src, (svoid_t*)dst, 16, 0, 0);
    }
  };

  const int nt = KS / KC;
  stage(0, k0);
  __syncthreads();

  for (int t = 0; t < nt; ++t) {
    const int cur = t & 1;
    if (t + 1 < nt) stage(cur ^ 1, k0 + (t + 1) * KC);  // prefetch next tile

    const float* wb = W + (size_t)ew0 * DIM + (k0 + t * KC);  // uniform
    const float* xrow = &xlds[cur][lane * KC];

#pragma unroll 4
    for (int c = 0; c < KC / 4; ++c) {
      const float4 xf = *(const float4*)(xrow + 4 * (c ^ key));
#pragma unroll
      for (int j = 0; j < TN; ++j) {
        const float4 w4 = *(const float4*)(wb + (size_t)j * DIM + 4 * c);
        acc[j] = fmaf(xf.x, w4.x, acc[j]);
        acc[j] = fmaf(xf.y, w4.y, acc[j]);
        acc[j] = fmaf(xf.z, w4.z, acc[j]);
        acc[j] = fmaf(xf.w, w4.w, acc[j]);
      }
    }
    __syncthreads();  // drains stage glds; closes buffer reuse
  }

  // write P[split][token][ew0..ew0+15] (64B contiguous per lane)
  float* prow = P + ((size_t)blockIdx.y * N_TOKENS + tok0 + lane) * NEXP + ew0;
#pragma unroll
  for (int q = 0; q < TN / 4; ++q) {
    float4 o;
    o.x = acc[q * 4 + 0];
    o.y = acc[q * 4 + 1];
    o.z = acc[q * 4 + 2];
    o.w = acc[q * 4 + 3];
    *(float4*)(prow + q * 4) = o;
  }
}

// ------------- K2: sum partials, softmax, top-2, chunk histograms -------------
__global__ __launch_bounds__(128) void k2_softmax_top2(const float* __restrict__ P,
                                                       int split,
                                                       float* __restrict__ topw,
                                                       int* __restrict__ sel,
                                                       int* __restrict__ cnt) {
  __shared__ int hist[NEXP];
  const int tid = threadIdx.x;
  const int t = blockIdx.x * 128 + tid;
  if (tid < NEXP) hist[tid] = 0;
  __syncthreads();

  float4 v[16];
  {
    const float* row = P + (size_t)t * NEXP;
#pragma unroll
    for (int c = 0; c < 16; ++c) v[c] = *(const float4*)(row + c * 4);
  }
  for (int s = 1; s < split; ++s) {
    const float* row = P + ((size_t)s * N_TOKENS + t) * NEXP;
#pragma unroll
    for (int c = 0; c < 16; ++c) {
      const float4 u = *(const float4*)(row + c * 4);
      v[c].x += u.x; v[c].y += u.y; v[c].z += u.z; v[c].w += u.w;
    }
  }

  float v0 = -INFINITY, v1 = -INFINITY;
  int i0 = 0, i1 = 0;
#define TOP2_STEP(val, idx)                                   \
  {                                                           \
    const float vv = (val);                                   \
    const int ee = (idx);                                     \
    if (vv > v0) { v1 = v0; i1 = i0; v0 = vv; i0 = ee; }      \
    else if (vv > v1) { v1 = vv; i1 = ee; }                   \
  }
#pragma unroll
  for (int c = 0; c < 16; ++c) {
    TOP2_STEP(v[c].x, c * 4 + 0);
    TOP2_STEP(v[c].y, c * 4 + 1);
    TOP2_STEP(v[c].z, c * 4 + 2);
    TOP2_STEP(v[c].w, c * 4 + 3);
  }
#undef TOP2_STEP

  float denom = 0.f;
#pragma unroll
  for (int c = 0; c < 16; ++c) {
    denom += expf(v[c].x - v0);
    denom += expf(v[c].y - v0);
    denom += expf(v[c].z - v0);
    denom += expf(v[c].w - v0);
  }
  const float w0 = 1.0f / denom;           // expf(0) == 1 exactly
  const float w1 = expf(v1 - v0) / denom;

  topw[t * 2 + 0] = w0;
  topw[t * 2 + 1] = w1;
  sel[t * 2 + 0] = i0;
  sel[t * 2 + 1] = i1;
  atomicAdd(&hist[i0], 1);
  atomicAdd(&hist[i1], 1);
  __syncthreads();
  if (tid < NEXP) cnt[blockIdx.x * NEXP + tid] = hist[tid];
}

// -------- K3: expert totals (counts out), exclusive offsets, chunk bases --------
__global__ void k3_scan(const int* __restrict__ cnt, int* __restrict__ cb,
                        float* __restrict__ counts_out) {
  __shared__ int tot[NEXP];
  const int e = threadIdx.x;  // 64 threads
  int run = 0;
  for (int p = 0; p < 128; ++p) run += cnt[p * NEXP + e];
  tot[e] = run;
  counts_out[e] = (float)run;
  __syncthreads();
  int g = 0;
  for (int q = 0; q < e; ++q) g += tot[q];
  int r = g;
  for (int p = 0; p < 128; ++p) {
    cb[p * NEXP + e] = r;
    r += cnt[p * NEXP + e];
  }
}

// ---------------- K4: stable scatter (counting-sort permutation) ----------------
__global__ __launch_bounds__(256) void k4_scatter(const int* __restrict__ sel,
                                                  const int* __restrict__ cb,
                                                  float* __restrict__ gout) {
  __shared__ int wcnt[4 * NEXP];
  const int tid = threadIdx.x;
  const int s = blockIdx.x * 256 + tid;
  const int e = sel[s];
  const int lane = tid & 63;
  const int wv = tid >> 6;
  wcnt[tid] = 0;
  __syncthreads();

  unsigned long long mask = ~0ull;
#pragma unroll
  for (int b = 0; b < 6; ++b) {
    const unsigned long long bb = __ballot((e >> b) & 1);
    mask &= ((e >> b) & 1) ? bb : ~bb;
  }
  const unsigned long long below = mask & ((1ull << lane) - 1ull);
  const int wr = __popcll(below);
  if (wr == 0) wcnt[wv * NEXP + e] = __popcll(mask);
  __syncthreads();

  int base = cb[blockIdx.x * NEXP + e];
  for (int w2 = 0; w2 < wv; ++w2) base += wcnt[w2 * NEXP + e];
  gout[base + wr] = (float)s;
}

extern "C" void kernel_launch(void* const* d_in, const int* in_sizes, int n_in,
                              void* d_out, int out_size, void* d_ws, size_t ws_size,
                              hipStream_t stream) {
  const float* x = (const float*)d_in[0];
  const float* W = (const float*)d_in[1];
  float* out = (float*)d_out;

  auto need = [](int s) {
    return (size_t)s * N_TOKENS * NEXP * 4 + (size_t)N_TOKENS * 2 * 4 +
           2 * (size_t)128 * NEXP * 4;
  };
  int split = 8;
  if (ws_size < need(8)) split = 4;
  if (ws_size < need(4)) split = (ws_size >= need(2)) ? 2 : 1;
  const int KS = DIM / split;

  float* P = (float*)d_ws;
  int* sel = (int*)((char*)d_ws + (size_t)split * N_TOKENS * NEXP * 4);
  int* cnt = sel + N_TOKENS * 2;
  int* cb = cnt + 128 * NEXP;

  hipLaunchKernelGGL(k1_gemm, dim3(N_TOKENS / MT, split), dim3(256), 0, stream,
                     x, W, P, KS);
  hipLaunchKernelGGL(k2_softmax_top2, dim3(N_TOKENS / 128), dim3(128), 0, stream,
                     P, split, out, sel, cnt);
  hipLaunchKernelGGL(k3_scan, dim3(1), dim3(64), 0, stream, cnt, cb,
                     out + 2 * N_TOKENS + 2 * N_TOKENS);
  hipLaunchKernelGGL(k4_scatter, dim3((2 * N_TOKENS) / 256), dim3(256), 0, stream,
                     sel, cb, out + 2 * N_TOKENS);
}

// Round 7
// 273.163 us; speedup vs baseline: 2.6487x; 2.6487x over previous
//
#include <hip/hip_runtime.h>
#include <hip/hip_bf16.h>
#include <math.h>
#include <stdint.h>

#define N_TOKENS 16384
#define DIM 4096
#define NEXP 64

typedef const __attribute__((address_space(1))) void gvoid_t;
typedef __attribute__((address_space(3))) void svoid_t;

constexpr int KC = 32;   // k per staged chunk (8 x 16B slots per row)
constexpr int TM = 32;   // tokens per wave (one acc VGPR each)
constexpr int MT = 128;  // tokens per block (4 waves)

// ---------------- K1: logits = x @ W^T (fp32, K-split partials) ----------------
// lane = EXPERT. Wave holds W[lane][kc..kc+KC] in 32 VGPRs (8 swizzled
// ds_read_b128 = byte-floor 8cy each); x rows are read as WAVE-UNIFORM
// broadcast ds_read_b128 (1cy). One v_fma covers all 64 experts -> LDS
// traffic per FMA cycle is ~6%: FMA-bound by construction.
// x double-buffered (2x16KB) + W single-buffered (8KB) = 40KB -> 4 blocks/CU.
// Chunk: loadWregs | barrier A | stage W(t+1),x(t+1) | 1024 FMA | barrier B.
__global__ __launch_bounds__(256, 4) void k1_gemm(const float* __restrict__ x,
                                                  const float* __restrict__ W,
                                                  float* __restrict__ P, int KS) {
  __shared__ float xlds[2][MT * KC];  // linear [row][k/4 slots], 2 x 16 KB
  __shared__ float wlds[NEXP * KC];   // slot-swizzled [row][slot^(row&7)], 8 KB
  const int tid = threadIdx.x;
  const int lane = tid & 63;  // expert id
  const int wid = __builtin_amdgcn_readfirstlane(tid >> 6);  // wave 0..3
  const int tok0 = blockIdx.x * MT;
  const int k0 = blockIdx.y * KS;

  const int lr = lane >> 3;  // row offset within one glds instr (8 rows x 128B)
  const int ls = lane & 7;   // 16B slot within row

  float acc[TM] = {};

  // stage x[tok0..+127][kc..+31]: 4 glds/wave, 8 rows (1KB) each, LINEAR.
  auto stage_x = [&](int b, int kc) {
#pragma unroll
    for (int q = 0; q < 4; ++q) {
      const int r0 = wid * 32 + q * 8;  // wave-uniform row base
      const int r = r0 + lr;
      const float* src = x + (size_t)(tok0 + r) * DIM + kc + 4 * ls;
      float* dst = &xlds[b][r0 * KC];
      __builtin_amdgcn_global_load_lds((gvoid_t*)src, (svoid_t*)dst, 16, 0, 0);
    }
  };
  // stage W[0..63][kc..+31]: 2 glds/wave; source slot-permuted (slot^(row&7)),
  // dest linear (rule 21 both-sides involution with the compute read below).
  auto stage_w = [&](int kc) {
#pragma unroll
    for (int q = 0; q < 2; ++q) {
      const int r0 = wid * 16 + q * 8;  // wave-uniform row base
      const int r = r0 + lr;
      const float* src = W + (size_t)r * DIM + kc + 4 * (ls ^ (r & 7));
      float* dst = &wlds[r0 * KC];
      __builtin_amdgcn_global_load_lds((gvoid_t*)src, (svoid_t*)dst, 16, 0, 0);
    }
  };

  const int nt = KS / KC;
  stage_x(0, k0);
  stage_w(k0);
  __syncthreads();  // vmcnt drained at barrier

  for (int t = 0; t < nt; ++t) {
    const int cur = t & 1;

    // W[lane][kc..kc+32] -> 8 swizzled b128 reads (8-way = byte floor)
    float4 wreg[8];
#pragma unroll
    for (int c = 0; c < 8; ++c)
      wreg[c] = *(const float4*)(wlds + lane * KC + 4 * (c ^ (lane & 7)));

    __syncthreads();  // A: all waves done reading wlds (lgkm drained)

    if (t + 1 < nt) {  // stages overlap the FMA loop below
      stage_w(k0 + (t + 1) * KC);
      stage_x(cur ^ 1, k0 + (t + 1) * KC);
    }

    // 32 tokens x 32 k: x broadcast (uniform addr), 1024 scalar v_fma
#pragma unroll
    for (int i = 0; i < TM; ++i) {
      const float* xr = &xlds[cur][(wid * TM + i) * KC];
#pragma unroll
      for (int c = 0; c < 8; ++c) {
        const float4 xv = *(const float4*)(xr + 4 * c);
        acc[i] = fmaf(xv.x, wreg[c].x, acc[i]);
        acc[i] = fmaf(xv.y, wreg[c].y, acc[i]);
        acc[i] = fmaf(xv.z, wreg[c].z, acc[i]);
        acc[i] = fmaf(xv.w, wreg[c].w, acc[i]);
      }
    }
    __syncthreads();  // B: drains stage glds; closes xlds[cur] reuse
  }

  // write P[split][tok][lane]: 64 contiguous floats per token row
  float* pbase = P + ((size_t)blockIdx.y * N_TOKENS + tok0 + wid * TM) * NEXP + lane;
#pragma unroll
  for (int i = 0; i < TM; ++i) pbase[i * NEXP] = acc[i];
}

// ------------- K2: sum partials, softmax, top-2, chunk histograms -------------
__global__ __launch_bounds__(128) void k2_softmax_top2(const float* __restrict__ P,
                                                       int split,
                                                       float* __restrict__ topw,
                                                       int* __restrict__ sel,
                                                       int* __restrict__ cnt) {
  __shared__ int hist[NEXP];
  const int tid = threadIdx.x;
  const int t = blockIdx.x * 128 + tid;
  if (tid < NEXP) hist[tid] = 0;
  __syncthreads();

  float4 v[16];
  {
    const float* row = P + (size_t)t * NEXP;
#pragma unroll
    for (int c = 0; c < 16; ++c) v[c] = *(const float4*)(row + c * 4);
  }
  for (int s = 1; s < split; ++s) {
    const float* row = P + ((size_t)s * N_TOKENS + t) * NEXP;
#pragma unroll
    for (int c = 0; c < 16; ++c) {
      const float4 u = *(const float4*)(row + c * 4);
      v[c].x += u.x; v[c].y += u.y; v[c].z += u.z; v[c].w += u.w;
    }
  }

  float v0 = -INFINITY, v1 = -INFINITY;
  int i0 = 0, i1 = 0;
#define TOP2_STEP(val, idx)                                   \
  {                                                           \
    const float vv = (val);                                   \
    const int ee = (idx);                                     \
    if (vv > v0) { v1 = v0; i1 = i0; v0 = vv; i0 = ee; }      \
    else if (vv > v1) { v1 = vv; i1 = ee; }                   \
  }
#pragma unroll
  for (int c = 0; c < 16; ++c) {
    TOP2_STEP(v[c].x, c * 4 + 0);
    TOP2_STEP(v[c].y, c * 4 + 1);
    TOP2_STEP(v[c].z, c * 4 + 2);
    TOP2_STEP(v[c].w, c * 4 + 3);
  }
#undef TOP2_STEP

  float denom = 0.f;
#pragma unroll
  for (int c = 0; c < 16; ++c) {
    denom += expf(v[c].x - v0);
    denom += expf(v[c].y - v0);
    denom += expf(v[c].z - v0);
    denom += expf(v[c].w - v0);
  }
  const float w0 = 1.0f / denom;           // expf(0) == 1 exactly
  const float w1 = expf(v1 - v0) / denom;

  topw[t * 2 + 0] = w0;
  topw[t * 2 + 1] = w1;
  sel[t * 2 + 0] = i0;
  sel[t * 2 + 1] = i1;
  atomicAdd(&hist[i0], 1);
  atomicAdd(&hist[i1], 1);
  __syncthreads();
  if (tid < NEXP) cnt[blockIdx.x * NEXP + tid] = hist[tid];
}

// -------- K3: expert totals (counts out), exclusive offsets, chunk bases --------
__global__ void k3_scan(const int* __restrict__ cnt, int* __restrict__ cb,
                        float* __restrict__ counts_out) {
  __shared__ int tot[NEXP];
  const int e = threadIdx.x;  // 64 threads
  int run = 0;
  for (int p = 0; p < 128; ++p) run += cnt[p * NEXP + e];
  tot[e] = run;
  counts_out[e] = (float)run;
  __syncthreads();
  int g = 0;
  for (int q = 0; q < e; ++q) g += tot[q];
  int r = g;
  for (int p = 0; p < 128; ++p) {
    cb[p * NEXP + e] = r;
    r += cnt[p * NEXP + e];
  }
}

// ---------------- K4: stable scatter (counting-sort permutation) ----------------
__global__ __launch_bounds__(256) void k4_scatter(const int* __restrict__ sel,
                                                  const int* __restrict__ cb,
                                                  float* __restrict__ gout) {
  __shared__ int wcnt[4 * NEXP];
  const int tid = threadIdx.x;
  const int s = blockIdx.x * 256 + tid;
  const int e = sel[s];
  const int lane = tid & 63;
  const int wv = tid >> 6;
  wcnt[tid] = 0;
  __syncthreads();

  unsigned long long mask = ~0ull;
#pragma unroll
  for (int b = 0; b < 6; ++b) {
    const unsigned long long bb = __ballot((e >> b) & 1);
    mask &= ((e >> b) & 1) ? bb : ~bb;
  }
  const unsigned long long below = mask & ((1ull << lane) - 1ull);
  const int wr = __popcll(below);
  if (wr == 0) wcnt[wv * NEXP + e] = __popcll(mask);
  __syncthreads();

  int base = cb[blockIdx.x * NEXP + e];
  for (int w2 = 0; w2 < wv; ++w2) base += wcnt[w2 * NEXP + e];
  gout[base + wr] = (float)s;
}

extern "C" void kernel_launch(void* const* d_in, const int* in_sizes, int n_in,
                              void* d_out, int out_size, void* d_ws, size_t ws_size,
                              hipStream_t stream) {
  const float* x = (const float*)d_in[0];
  const float* W = (const float*)d_in[1];
  float* out = (float*)d_out;

  auto need = [](int s) {
    return (size_t)s * N_TOKENS * NEXP * 4 + (size_t)N_TOKENS * 2 * 4 +
           2 * (size_t)128 * NEXP * 4;
  };
  int split = 8;
  if (ws_size < need(8)) split = 4;
  if (ws_size < need(4)) split = (ws_size >= need(2)) ? 2 : 1;
  const int KS = DIM / split;

  float* P = (float*)d_ws;
  int* sel = (int*)((char*)d_ws + (size_t)split * N_TOKENS * NEXP * 4);
  int* cnt = sel + N_TOKENS * 2;
  int* cb = cnt + 128 * NEXP;

  hipLaunchKernelGGL(k1_gemm, dim3(N_TOKENS / MT, split), dim3(256), 0, stream,
                     x, W, P, KS);
  hipLaunchKernelGGL(k2_softmax_top2, dim3(N_TOKENS / 128), dim3(128), 0, stream,
                     P, split, out, sel, cnt);
  hipLaunchKernelGGL(k3_scan, dim3(1), dim3(64), 0, stream, cnt, cb,
                     out + 2 * N_TOKENS + 2 * N_TOKENS);
  hipLaunchKernelGGL(k4_scatter, dim3((2 * N_TOKENS) / 256), dim3(256), 0, stream,
                     sel, cb, out + 2 * N_TOKENS);
}